// Round 3
// baseline (314.127 us; speedup 1.0000x reference)
//
#include <hip/hip_runtime.h>
#include <math.h>

#define TLEN 4096
#define BD   1024
#define HDIM 64
#define NB   4

typedef __attribute__((ext_vector_type(8))) short bf16x8;
typedef __attribute__((ext_vector_type(4))) float f32x4;

__device__ __forceinline__ unsigned short f2bf(float f) {
    union { float f; unsigned u; } v; v.f = f;
    unsigned r = v.u + 0x7FFF + ((v.u >> 16) & 1);   // RNE
    return (unsigned short)(r >> 16);
}

// pure-register fp32x8 -> bf16x8 (no local arrays -> no scratch risk)
__device__ __forceinline__ bf16x8 cvt8(const float4 a, const float4 b) {
    bf16x8 r;
    r[0] = (short)f2bf(a.x); r[1] = (short)f2bf(a.y);
    r[2] = (short)f2bf(a.z); r[3] = (short)f2bf(a.w);
    r[4] = (short)f2bf(b.x); r[5] = (short)f2bf(b.y);
    r[6] = (short)f2bf(b.z); r[7] = (short)f2bf(b.w);
    return r;
}

// ---------------------------------------------------------------------------
// Kernel 0: weights fp32 -> bf16, wbf[192][1024] (rows 0-63 Q, 64-127 K, 128-191 V)
// ---------------------------------------------------------------------------
__global__ __launch_bounds__(256) void wconv_kernel(
    const float* __restrict__ wq, const float* __restrict__ wk,
    const float* __restrict__ wv, unsigned short* __restrict__ wbf)
{
    const int r = blockIdx.x;                 // 0..191
    const float* src = (r < 64) ? wq : (r < 128) ? wk : wv;
    const int rr = r & 63;
    const int c  = threadIdx.x * 4;
    float4 a = *(const float4*)&src[(size_t)rr * BD + c];
    uint2 o;
    o.x = (unsigned)f2bf(a.x) | ((unsigned)f2bf(a.y) << 16);
    o.y = (unsigned)f2bf(a.z) | ((unsigned)f2bf(a.w) << 16);
    *(uint2*)&wbf[(size_t)r * BD + c] = o;
}

// ---------------------------------------------------------------------------
// Kernel 1: QKV projection. 1024 one-wave blocks, 16 rows/wave, no barriers,
// no LDS in the K-loop. A from x (fp32->bf16 regs), B direct from wbf (L2).
// Outputs: Q,K bf16 [t][64]; V bf16 transposed [b][64][4096].
// ---------------------------------------------------------------------------
__global__ __launch_bounds__(64) void qkv_kernel(
    const float* __restrict__ x,
    const unsigned short* __restrict__ wbf,
    unsigned short* __restrict__ Qb,
    unsigned short* __restrict__ Kb,
    unsigned short* __restrict__ Vt)
{
    const int r0   = blockIdx.x * 16;
    const int lane = threadIdx.x;
    const int g    = lane >> 4;
    const int c    = lane & 15;

    const float* xrow = x + (size_t)(r0 + c) * BD + g * 8;
    const unsigned short* wp[12];
    #pragma unroll
    for (int t = 0; t < 12; ++t)
        wp[t] = wbf + (size_t)(16 * t + c) * BD + g * 8;

    f32x4 acc[12];
    #pragma unroll
    for (int t = 0; t < 12; ++t) acc[t] = (f32x4){0.f, 0.f, 0.f, 0.f};

    #pragma unroll 4
    for (int k0 = 0; k0 < BD; k0 += 32) {
        float4 xa = *(const float4*)(xrow + k0);
        float4 xb = *(const float4*)(xrow + k0 + 4);
        bf16x8 aF = cvt8(xa, xb);
        #pragma unroll
        for (int t = 0; t < 12; ++t) {
            bf16x8 bF = *(const bf16x8*)(wp[t] + k0);
            acc[t] = __builtin_amdgcn_mfma_f32_16x16x32_bf16(aF, bF, acc[t], 0, 0, 0);
        }
    }

    // epilogue. C/D: row = g*4+i (q-row), col = c (+16t outdim)
    #pragma unroll
    for (int t = 0; t < 4; ++t)
        #pragma unroll
        for (int i = 0; i < 4; ++i) {
            Qb[(size_t)(r0 + g * 4 + i) * HDIM + 16 * t + c] = f2bf(acc[t][i]);
            Kb[(size_t)(r0 + g * 4 + i) * HDIM + 16 * t + c] = f2bf(acc[4 + t][i]);
        }

    // V: transpose through wave LDS, then 32B rows out
    __shared__ __align__(16) unsigned short vls[64][24];  // stride 48B (16B-aligned)
    #pragma unroll
    for (int t = 0; t < 4; ++t)
        #pragma unroll
        for (int i = 0; i < 4; ++i)
            vls[16 * t + c][g * 4 + i] = f2bf(acc[8 + t][i]);
    __syncthreads();   // one-wave block: cheap, guarantees LDS visibility
    const int bb   = r0 / TLEN;
    const int trow = r0 % TLEN;
    uint4 v0 = *(const uint4*)&vls[lane][0];
    uint4 v1 = *(const uint4*)&vls[lane][8];
    unsigned short* vdst = Vt + (size_t)bb * HDIM * TLEN + (size_t)lane * TLEN + trow;
    *(uint4*)&vdst[0] = v0;
    *(uint4*)&vdst[8] = v1;
}

// ---------------------------------------------------------------------------
// Kernel 2: flash attention, one-wave blocks, 16 q-rows/wave, barrier-free.
// KEYS = keys per split. KEYS==TLEN: write normalized out directly.
// KEYS<TLEN: split 0 -> unnormalized O in `out`, split 1 -> O1; (m,l) -> Ml.
// ---------------------------------------------------------------------------
template <int KEYS>
__global__ __launch_bounds__(64) void attn_kernel(
    const unsigned short* __restrict__ Qb,
    const unsigned short* __restrict__ Kb,
    const unsigned short* __restrict__ Vt,
    float* __restrict__ O1, float* __restrict__ Ml, float* __restrict__ out)
{
    const int b     = blockIdx.y;
    const int q0    = blockIdx.x * 16;
    const int split = blockIdx.z;
    const int sbase = split * KEYS;

    const unsigned short* Qp = Qb + (size_t)b * TLEN * HDIM;
    const unsigned short* Kp = Kb + (size_t)b * TLEN * HDIM + (size_t)sbase * HDIM;
    const unsigned short* Vp = Vt + (size_t)b * HDIM * TLEN + sbase;

    const int lane = threadIdx.x;
    const int g    = lane >> 4;
    const int c    = lane & 15;

    bf16x8 qA0 = *(const bf16x8*)&Qp[(size_t)(q0 + c) * HDIM + g * 8];
    bf16x8 qA1 = *(const bf16x8*)&Qp[(size_t)(q0 + c) * HDIM + 32 + g * 8];

    __shared__ __align__(16) unsigned short pp[16][72];

    float mrow[4], lsum[4];
    f32x4 oacc[4];
    #pragma unroll
    for (int i = 0; i < 4; ++i) { mrow[i] = -INFINITY; lsum[i] = 0.f; }
    #pragma unroll
    for (int t = 0; t < 4; ++t) oacc[t] = (f32x4){0.f, 0.f, 0.f, 0.f};

    for (int s0 = 0; s0 < KEYS; s0 += 64) {
        // S = Q K^T  (16 q-rows x 64 keys), K frags direct from global
        f32x4 sacc[4];
        #pragma unroll
        for (int t = 0; t < 4; ++t) sacc[t] = (f32x4){0.f, 0.f, 0.f, 0.f};
        #pragma unroll
        for (int t = 0; t < 4; ++t) {
            bf16x8 kB0 = *(const bf16x8*)&Kp[(size_t)(s0 + 16 * t + c) * HDIM + g * 8];
            bf16x8 kB1 = *(const bf16x8*)&Kp[(size_t)(s0 + 16 * t + c) * HDIM + 32 + g * 8];
            sacc[t] = __builtin_amdgcn_mfma_f32_16x16x32_bf16(qA0, kB0, sacc[t], 0, 0, 0);
            sacc[t] = __builtin_amdgcn_mfma_f32_16x16x32_bf16(qA1, kB1, sacc[t], 0, 0, 0);
        }

        // online softmax; C row = g*4+i, reduce over the 16-lane col group
        #pragma unroll
        for (int i = 0; i < 4; ++i) {
            float tm = fmaxf(fmaxf(sacc[0][i], sacc[1][i]),
                             fmaxf(sacc[2][i], sacc[3][i])) * 0.125f;
            tm = fmaxf(tm, __shfl_xor(tm, 1));
            tm = fmaxf(tm, __shfl_xor(tm, 2));
            tm = fmaxf(tm, __shfl_xor(tm, 4));
            tm = fmaxf(tm, __shfl_xor(tm, 8));
            const float newm  = fmaxf(mrow[i], tm);
            const float alpha = __expf(mrow[i] - newm);
            float pr[4];
            float rs = 0.f;
            #pragma unroll
            for (int t = 0; t < 4; ++t) {
                pr[t] = __expf(fmaf(sacc[t][i], 0.125f, -newm));
                rs += pr[t];
            }
            rs += __shfl_xor(rs, 1);
            rs += __shfl_xor(rs, 2);
            rs += __shfl_xor(rs, 4);
            rs += __shfl_xor(rs, 8);
            lsum[i] = lsum[i] * alpha + rs;
            mrow[i] = newm;
            #pragma unroll
            for (int t = 0; t < 4; ++t) oacc[t][i] *= alpha;
            #pragma unroll
            for (int t = 0; t < 4; ++t)
                pp[g * 4 + i][c + 16 * t] = f2bf(pr[t]);   // wave-private, no barrier
        }

        // O += P V ; V frags direct from Vt[d][t]
        bf16x8 pA0 = *(const bf16x8*)&pp[c][g * 8];
        bf16x8 pA1 = *(const bf16x8*)&pp[c][32 + g * 8];
        #pragma unroll
        for (int t = 0; t < 4; ++t) {
            bf16x8 vB0 = *(const bf16x8*)&Vp[(size_t)(16 * t + c) * TLEN + s0 + g * 8];
            bf16x8 vB1 = *(const bf16x8*)&Vp[(size_t)(16 * t + c) * TLEN + s0 + 32 + g * 8];
            oacc[t] = __builtin_amdgcn_mfma_f32_16x16x32_bf16(pA0, vB0, oacc[t], 0, 0, 0);
            oacc[t] = __builtin_amdgcn_mfma_f32_16x16x32_bf16(pA1, vB1, oacc[t], 0, 0, 0);
        }
    }

    if (KEYS == TLEN) {
        #pragma unroll
        for (int i = 0; i < 4; ++i) {
            const float inv = 1.0f / lsum[i];
            #pragma unroll
            for (int t = 0; t < 4; ++t)
                out[(size_t)(b * TLEN + q0 + g * 4 + i) * HDIM + 16 * t + c]
                    = oacc[t][i] * inv;
        }
    } else {
        float* Od = (split == 0) ? out : O1;   // split 0 parks in d_out
        #pragma unroll
        for (int i = 0; i < 4; ++i)
            #pragma unroll
            for (int t = 0; t < 4; ++t)
                Od[(size_t)(b * TLEN + q0 + g * 4 + i) * HDIM + 16 * t + c]
                    = oacc[t][i];
        if (c == 0) {
            #pragma unroll
            for (int i = 0; i < 4; ++i) {
                const size_t r = ((size_t)(split * NB + b) * TLEN + q0 + g * 4 + i) * 2;
                Ml[r]     = mrow[i];
                Ml[r + 1] = lsum[i];
            }
        }
    }
}

// ---------------------------------------------------------------------------
// Kernel 3: merge the two splits (in-place on d_out). 1 thread = 4 floats.
// ---------------------------------------------------------------------------
__global__ __launch_bounds__(256) void merge_kernel(
    float* __restrict__ out, const float* __restrict__ O1,
    const float* __restrict__ Ml)
{
    const int idx  = blockIdx.x * 256 + threadIdx.x;
    const int row  = idx >> 4;             // 0..16383
    const int col4 = (idx & 15) * 4;
    const int b    = row >> 12;
    const int t    = row & (TLEN - 1);
    const float m0 = Ml[((size_t)(0 * NB + b) * TLEN + t) * 2];
    const float l0 = Ml[((size_t)(0 * NB + b) * TLEN + t) * 2 + 1];
    const float m1 = Ml[((size_t)(1 * NB + b) * TLEN + t) * 2];
    const float l1 = Ml[((size_t)(1 * NB + b) * TLEN + t) * 2 + 1];
    const float M  = fmaxf(m0, m1);
    const float w0 = __expf(m0 - M);
    const float w1 = __expf(m1 - M);
    const float inv = 1.0f / fmaf(w0, l0, w1 * l1);
    float4 a = *(const float4*)&out[(size_t)row * HDIM + col4];
    float4 bq = *(const float4*)&O1[(size_t)row * HDIM + col4];
    float4 r;
    r.x = (a.x * w0 + bq.x * w1) * inv;
    r.y = (a.y * w0 + bq.y * w1) * inv;
    r.z = (a.z * w0 + bq.z * w1) * inv;
    r.w = (a.w * w0 + bq.w * w1) * inv;
    *(float4*)&out[(size_t)row * HDIM + col4] = r;
}

// ---------------------------------------------------------------------------
extern "C" void kernel_launch(void* const* d_in, const int* in_sizes, int n_in,
                              void* d_out, int out_size, void* d_ws, size_t ws_size,
                              hipStream_t stream)
{
    (void)in_sizes; (void)n_in; (void)out_size;
    const float* x  = (const float*)d_in[0];
    const float* wq = (const float*)d_in[1];
    const float* wk = (const float*)d_in[2];
    const float* wv = (const float*)d_in[3];
    float* out = (float*)d_out;

    // bf16 weights parked in d_out (384 KB of 4 MB; overwritten by attn/merge)
    unsigned short* wbf = (unsigned short*)d_out;
    unsigned short* Qbf = (unsigned short*)d_ws;
    unsigned short* Kbf = Qbf + (size_t)NB * TLEN * HDIM;
    unsigned short* Vtb = Kbf + (size_t)NB * TLEN * HDIM;
    float* Ml = (float*)((char*)d_ws + (size_t)3 * NB * TLEN * HDIM * 2);
    float* O1 = Ml + (size_t)2 * NB * TLEN * 2;
    const size_t ws_need_split = (size_t)3 * NB * TLEN * HDIM * 2   // QKV bf16
                               + (size_t)2 * NB * TLEN * 2 * 4      // Ml
                               + (size_t)NB * TLEN * HDIM * 4;      // O1
    const bool use_split = ws_size >= ws_need_split;

    wconv_kernel<<<dim3(192), 256, 0, stream>>>(wq, wk, wv, wbf);
    qkv_kernel<<<dim3(NB * TLEN / 16), 64, 0, stream>>>(x, wbf, Qbf, Kbf, Vtb);

    if (use_split) {
        attn_kernel<TLEN / 2><<<dim3(TLEN / 16, NB, 2), 64, 0, stream>>>(
            Qbf, Kbf, Vtb, O1, Ml, out);
        merge_kernel<<<dim3(NB * TLEN * 16 / 256), 256, 0, stream>>>(out, O1, Ml);
    } else {
        attn_kernel<TLEN><<<dim3(TLEN / 16, NB, 1), 64, 0, stream>>>(
            Qbf, Kbf, Vtb, O1, Ml, out);
    }
}

// Round 4
// 184.479 us; speedup vs baseline: 1.7028x; 1.7028x over previous
//
#include <hip/hip_runtime.h>
#include <math.h>

#define TLEN 4096
#define BD   1024
#define HDIM 64
#define NB   4

typedef __attribute__((ext_vector_type(8))) short bf16x8;
typedef __attribute__((ext_vector_type(4))) float f32x4;

typedef const __attribute__((address_space(1))) unsigned char* gp_t;
typedef __attribute__((address_space(3))) unsigned char* lp_t;

// async global->LDS, 16 B per lane; LDS dest must be wave-uniform base + lane*16
__device__ __forceinline__ void async_cp16(const void* g, void* l) {
    __builtin_amdgcn_global_load_lds((gp_t)g, (lp_t)l, 16, 0, 0);
}

__device__ __forceinline__ unsigned short f2bf(float f) {
    union { float f; unsigned u; } v; v.f = f;
    unsigned r = v.u + 0x7FFF + ((v.u >> 16) & 1);   // RNE
    return (unsigned short)(r >> 16);
}

__device__ __forceinline__ bf16x8 cvt8(const float4 a, const float4 b) {
    bf16x8 r;
    r[0] = (short)f2bf(a.x); r[1] = (short)f2bf(a.y);
    r[2] = (short)f2bf(a.z); r[3] = (short)f2bf(a.w);
    r[4] = (short)f2bf(b.x); r[5] = (short)f2bf(b.y);
    r[6] = (short)f2bf(b.z); r[7] = (short)f2bf(b.w);
    return r;
}

// ---------------------------------------------------------------------------
// Kernel 0: weights fp32 -> bf16, wbf[192][1024]
// ---------------------------------------------------------------------------
__global__ __launch_bounds__(256) void wconv_kernel(
    const float* __restrict__ wq, const float* __restrict__ wk,
    const float* __restrict__ wv, unsigned short* __restrict__ wbf)
{
    const int r = blockIdx.x;
    const float* src = (r < 64) ? wq : (r < 128) ? wk : wv;
    const int rr = r & 63;
    const int c  = threadIdx.x * 4;
    float4 a = *(const float4*)&src[(size_t)rr * BD + c];
    uint2 o;
    o.x = (unsigned)f2bf(a.x) | ((unsigned)f2bf(a.y) << 16);
    o.y = (unsigned)f2bf(a.z) | ((unsigned)f2bf(a.w) << 16);
    *(uint2*)&wbf[(size_t)r * BD + c] = o;
}

// ---------------------------------------------------------------------------
// Kernel 1: QKV projection. 1024 one-wave blocks, 16 rows/wave.
// Explicit 2-stage register double buffer, unroll 1 -> no spill (R3 lesson).
// Q written PRE-SCALED by 0.125*log2(e) so attention uses exp2 directly.
// ---------------------------------------------------------------------------
__global__ __launch_bounds__(64, 1) void qkv_kernel(
    const float* __restrict__ x,
    const unsigned short* __restrict__ wbf,
    unsigned short* __restrict__ Qb,
    unsigned short* __restrict__ Kb,
    unsigned short* __restrict__ Vt)
{
    const int r0   = blockIdx.x * 16;
    const int lane = threadIdx.x;
    const int g    = lane >> 4;
    const int c    = lane & 15;

    const float* xrow = x + (size_t)(r0 + c) * BD + g * 8;
    const unsigned short* wrow = wbf + (size_t)c * BD + g * 8;

    f32x4 acc[12];
    #pragma unroll
    for (int t = 0; t < 12; ++t) acc[t] = (f32x4){0.f, 0.f, 0.f, 0.f};

    float4 xa = *(const float4*)(xrow);
    float4 xb = *(const float4*)(xrow + 4);
    bf16x8 wf[12];
    #pragma unroll
    for (int t = 0; t < 12; ++t) wf[t] = *(const bf16x8*)(wrow + t * 16 * BD);

    #pragma unroll 1
    for (int k0 = 0; k0 < BD; k0 += 32) {
        const int kn = (k0 + 32 < BD) ? k0 + 32 : 0;   // dummy on last iter
        float4 xa2 = *(const float4*)(xrow + kn);
        float4 xb2 = *(const float4*)(xrow + kn + 4);
        bf16x8 wf2[12];
        #pragma unroll
        for (int t = 0; t < 12; ++t)
            wf2[t] = *(const bf16x8*)(wrow + t * 16 * BD + kn);

        bf16x8 aF = cvt8(xa, xb);
        #pragma unroll
        for (int t = 0; t < 12; ++t)
            acc[t] = __builtin_amdgcn_mfma_f32_16x16x32_bf16(aF, wf[t], acc[t], 0, 0, 0);

        xa = xa2; xb = xb2;
        #pragma unroll
        for (int t = 0; t < 12; ++t) wf[t] = wf2[t];
    }

    // epilogue. C/D: row = g*4+i, col = c (+16t)
    const float qscale = 0.18033688f;   // 0.125 * log2(e)
    #pragma unroll
    for (int t = 0; t < 4; ++t)
        #pragma unroll
        for (int i = 0; i < 4; ++i) {
            Qb[(size_t)(r0 + g * 4 + i) * HDIM + 16 * t + c] = f2bf(acc[t][i] * qscale);
            Kb[(size_t)(r0 + g * 4 + i) * HDIM + 16 * t + c] = f2bf(acc[4 + t][i]);
        }

    // V: transpose through wave LDS -> Vt[b][d][TLEN]
    __shared__ __align__(16) unsigned short vls[64][24];
    #pragma unroll
    for (int t = 0; t < 4; ++t)
        #pragma unroll
        for (int i = 0; i < 4; ++i)
            vls[16 * t + c][g * 4 + i] = f2bf(acc[8 + t][i]);
    __syncthreads();
    const int bb   = r0 / TLEN;
    const int trow = r0 % TLEN;
    uint4 v0 = *(const uint4*)&vls[lane][0];
    uint4 v1 = *(const uint4*)&vls[lane][8];
    unsigned short* vdst = Vt + (size_t)bb * HDIM * TLEN + (size_t)lane * TLEN + trow;
    *(uint4*)&vdst[0] = v0;
    *(uint4*)&vdst[8] = v1;
}

// ---------------------------------------------------------------------------
// Kernel 2: flash attention. 64q x 64k tiles, 4 waves (16q each),
// K/V double-buffered in LDS via global_load_lds w/ XOR row-swizzle,
// max-free softmax (logits provably bounded), exp2-only, deferred l-reduce.
// grid (TLEN/64, NB, splits).
// ---------------------------------------------------------------------------
template <int KEYS>
__global__ __launch_bounds__(256, 2) void attn_kernel(
    const unsigned short* __restrict__ Qb,
    const unsigned short* __restrict__ Kb,
    const unsigned short* __restrict__ Vt,
    float* __restrict__ O1, float* __restrict__ Ml, float* __restrict__ out)
{
    const int b     = blockIdx.y;
    const int q0    = blockIdx.x * 64;
    const int split = blockIdx.z;
    const int sbase = split * KEYS;

    const unsigned short* Qp = Qb + (size_t)b * TLEN * HDIM;
    const unsigned short* Kp = Kb + (size_t)b * TLEN * HDIM + (size_t)sbase * HDIM;
    const unsigned short* Vp = Vt + (size_t)b * HDIM * TLEN + sbase;

    const int tid  = threadIdx.x;
    const int lane = tid & 63;
    const int w    = tid >> 6;
    const int g    = lane >> 4;
    const int c    = lane & 15;

    // LDS: swizzled row-major [64][64] bf16 tiles (stored group j^=(row&7))
    __shared__ __align__(16) unsigned short ks[2][4096];
    __shared__ __align__(16) unsigned short vs[2][4096];
    __shared__ __align__(16) unsigned short pp[4][16 * 72];

    // Q frags direct from global (pre-scaled by 0.125*log2e in qkv)
    bf16x8 qA0 = *(const bf16x8*)&Qp[(size_t)(q0 + w * 16 + c) * HDIM + g * 8];
    bf16x8 qA1 = *(const bf16x8*)&Qp[(size_t)(q0 + w * 16 + c) * HDIM + 32 + g * 8];

    float lsum[4] = {0.f, 0.f, 0.f, 0.f};
    f32x4 oacc[4];
    #pragma unroll
    for (int t = 0; t < 4; ++t) oacc[t] = (f32x4){0.f, 0.f, 0.f, 0.f};

    const int nt = KEYS / 64;

    // ---- stage tile 0 into buf 0
    {
        const int s0 = 0;
        #pragma unroll
        for (int ii = 0; ii < 2; ++ii) {
            const int L   = ii * 256 + tid;
            const int row = L >> 3;
            const int jl  = (L & 7) ^ (row & 7);
            async_cp16(&Kp[(size_t)(s0 + row) * HDIM + jl * 8], &ks[0][L * 8]);
            async_cp16(&Vp[(size_t)row * TLEN + s0 + jl * 8],   &vs[0][L * 8]);
        }
    }

    for (int it = 0; it < nt; ++it) {
        const int cb = it & 1;
        __syncthreads();   // buf[cb] staged (vmcnt drained), prev reads done

        if (it + 1 < nt) {             // prefetch next tile into other buffer
            const int s0 = (it + 1) * 64;
            const int nb2 = cb ^ 1;
            #pragma unroll
            for (int ii = 0; ii < 2; ++ii) {
                const int L   = ii * 256 + tid;
                const int row = L >> 3;
                const int jl  = (L & 7) ^ (row & 7);
                async_cp16(&Kp[(size_t)(s0 + row) * HDIM + jl * 8], &ks[nb2][L * 8]);
                async_cp16(&Vp[(size_t)row * TLEN + s0 + jl * 8],   &vs[nb2][L * 8]);
            }
        }

        // ---- S = Q K^T (16q x 64k per wave); B-frags from swizzled LDS
        f32x4 sacc[4];
        #pragma unroll
        for (int t = 0; t < 4; ++t) sacc[t] = (f32x4){0.f, 0.f, 0.f, 0.f};
        #pragma unroll
        for (int t = 0; t < 4; ++t) {
            const int r  = 16 * t + c;
            const int j0 = g ^ (r & 7);
            bf16x8 kB0 = *(const bf16x8*)&ks[cb][(r * 8 + j0) * 8];
            bf16x8 kB1 = *(const bf16x8*)&ks[cb][(r * 8 + (j0 ^ 4)) * 8];
            sacc[t] = __builtin_amdgcn_mfma_f32_16x16x32_bf16(qA0, kB0, sacc[t], 0, 0, 0);
            sacc[t] = __builtin_amdgcn_mfma_f32_16x16x32_bf16(qA1, kB1, sacc[t], 0, 0, 0);
        }

        // ---- max-free softmax: p = 2^s (s pre-scaled); truncate to bf16,
        //      accumulate l from the truncated values (bias cancels in O/l)
        #pragma unroll
        for (int i = 0; i < 4; ++i) {
            float p0 = __builtin_amdgcn_exp2f(sacc[0][i]);
            float p1 = __builtin_amdgcn_exp2f(sacc[1][i]);
            float p2 = __builtin_amdgcn_exp2f(sacc[2][i]);
            float p3 = __builtin_amdgcn_exp2f(sacc[3][i]);
            unsigned u0 = __float_as_uint(p0) & 0xffff0000u;
            unsigned u1 = __float_as_uint(p1) & 0xffff0000u;
            unsigned u2 = __float_as_uint(p2) & 0xffff0000u;
            unsigned u3 = __float_as_uint(p3) & 0xffff0000u;
            lsum[i] += (__uint_as_float(u0) + __uint_as_float(u1))
                     + (__uint_as_float(u2) + __uint_as_float(u3));
            unsigned short* pr = &pp[w][(g * 4 + i) * 72 + c];
            pr[0]  = (unsigned short)(u0 >> 16);
            pr[16] = (unsigned short)(u1 >> 16);
            pr[32] = (unsigned short)(u2 >> 16);
            pr[48] = (unsigned short)(u3 >> 16);
        }

        // ---- O += P V  (A = P from wave-private LDS, B = V from swizzled LDS)
        bf16x8 pA0 = *(const bf16x8*)&pp[w][c * 72 + g * 8];
        bf16x8 pA1 = *(const bf16x8*)&pp[w][c * 72 + 32 + g * 8];
        #pragma unroll
        for (int t = 0; t < 4; ++t) {
            const int r  = 16 * t + c;
            const int j0 = g ^ (r & 7);
            bf16x8 vB0 = *(const bf16x8*)&vs[cb][(r * 8 + j0) * 8];
            bf16x8 vB1 = *(const bf16x8*)&vs[cb][(r * 8 + (j0 ^ 4)) * 8];
            oacc[t] = __builtin_amdgcn_mfma_f32_16x16x32_bf16(pA0, vB0, oacc[t], 0, 0, 0);
            oacc[t] = __builtin_amdgcn_mfma_f32_16x16x32_bf16(pA1, vB1, oacc[t], 0, 0, 0);
        }
    }

    // deferred cross-lane l reduction (over the 16 col lanes)
    #pragma unroll
    for (int i = 0; i < 4; ++i) {
        lsum[i] += __shfl_xor(lsum[i], 1);
        lsum[i] += __shfl_xor(lsum[i], 2);
        lsum[i] += __shfl_xor(lsum[i], 4);
        lsum[i] += __shfl_xor(lsum[i], 8);
    }

    const size_t orow = (size_t)(b * TLEN + q0 + w * 16 + g * 4);
    if (KEYS == TLEN) {
        #pragma unroll
        for (int i = 0; i < 4; ++i) {
            const float inv = 1.0f / lsum[i];
            #pragma unroll
            for (int t = 0; t < 4; ++t)
                out[(orow + i) * HDIM + 16 * t + c] = oacc[t][i] * inv;
        }
    } else {
        float* Od = (split == 0) ? out : O1;   // split 0 parks in d_out
        #pragma unroll
        for (int i = 0; i < 4; ++i)
            #pragma unroll
            for (int t = 0; t < 4; ++t)
                Od[(orow + i) * HDIM + 16 * t + c] = oacc[t][i];
        if (c == 0) {
            #pragma unroll
            for (int i = 0; i < 4; ++i)
                Ml[(size_t)(split * NB + b) * TLEN + q0 + w * 16 + g * 4 + i] = lsum[i];
        }
    }
}

// ---------------------------------------------------------------------------
// Kernel 3: merge splits: out = (O0 + O1) / (l0 + l1)
// ---------------------------------------------------------------------------
__global__ __launch_bounds__(256) void merge_kernel(
    float* __restrict__ out, const float* __restrict__ O1,
    const float* __restrict__ Ml)
{
    const int idx  = blockIdx.x * 256 + threadIdx.x;
    const int row  = idx >> 4;
    const int col4 = (idx & 15) * 4;
    const int b    = row >> 12;
    const int t    = row & (TLEN - 1);
    const float l0 = Ml[(size_t)b * TLEN + t];
    const float l1 = Ml[(size_t)(NB + b) * TLEN + t];
    const float inv = 1.0f / (l0 + l1);
    float4 a  = *(const float4*)&out[(size_t)row * HDIM + col4];
    float4 bq = *(const float4*)&O1[(size_t)row * HDIM + col4];
    float4 r;
    r.x = (a.x + bq.x) * inv;
    r.y = (a.y + bq.y) * inv;
    r.z = (a.z + bq.z) * inv;
    r.w = (a.w + bq.w) * inv;
    *(float4*)&out[(size_t)row * HDIM + col4] = r;
}

// ---------------------------------------------------------------------------
extern "C" void kernel_launch(void* const* d_in, const int* in_sizes, int n_in,
                              void* d_out, int out_size, void* d_ws, size_t ws_size,
                              hipStream_t stream)
{
    (void)in_sizes; (void)n_in; (void)out_size;
    const float* x  = (const float*)d_in[0];
    const float* wq = (const float*)d_in[1];
    const float* wk = (const float*)d_in[2];
    const float* wv = (const float*)d_in[3];
    float* out = (float*)d_out;

    unsigned short* wbf = (unsigned short*)d_out;     // parked; consumed by qkv
    unsigned short* Qbf = (unsigned short*)d_ws;
    unsigned short* Kbf = Qbf + (size_t)NB * TLEN * HDIM;
    unsigned short* Vtb = Kbf + (size_t)NB * TLEN * HDIM;
    float* Ml = (float*)((char*)d_ws + (size_t)3 * NB * TLEN * HDIM * 2);
    float* O1 = Ml + (size_t)2 * NB * TLEN;
    const size_t ws_need_split = (size_t)3 * NB * TLEN * HDIM * 2
                               + (size_t)2 * NB * TLEN * 4
                               + (size_t)NB * TLEN * HDIM * 4;
    const bool use_split = ws_size >= ws_need_split;

    wconv_kernel<<<dim3(192), 256, 0, stream>>>(wq, wk, wv, wbf);
    qkv_kernel<<<dim3(NB * TLEN / 16), 64, 0, stream>>>(x, wbf, Qbf, Kbf, Vtb);

    if (use_split) {
        attn_kernel<TLEN / 2><<<dim3(TLEN / 64, NB, 2), 256, 0, stream>>>(
            Qbf, Kbf, Vtb, O1, Ml, out);
        merge_kernel<<<dim3(NB * TLEN * 16 / 256), 256, 0, stream>>>(out, O1, Ml);
    } else {
        attn_kernel<TLEN><<<dim3(TLEN / 64, NB, 1), 256, 0, stream>>>(
            Qbf, Kbf, Vtb, O1, Ml, out);
    }
}

// Round 5
// 161.124 us; speedup vs baseline: 1.9496x; 1.1450x over previous
//
#include <hip/hip_runtime.h>
#include <math.h>

#define TLEN 4096
#define BD   1024
#define HDIM 64
#define NB   4

typedef __attribute__((ext_vector_type(8))) short bf16x8;
typedef __attribute__((ext_vector_type(4))) float f32x4;

typedef const __attribute__((address_space(1))) unsigned char* gp_t;
typedef __attribute__((address_space(3))) unsigned char* lp_t;

// async global->LDS, 16 B per lane; LDS dest must be wave-uniform base + lane*16
__device__ __forceinline__ void async_cp16(const void* g, void* l) {
    __builtin_amdgcn_global_load_lds((gp_t)g, (lp_t)l, 16, 0, 0);
}

__device__ __forceinline__ unsigned short f2bf(float f) {
    union { float f; unsigned u; } v; v.f = f;
    unsigned r = v.u + 0x7FFF + ((v.u >> 16) & 1);   // RNE
    return (unsigned short)(r >> 16);
}

__device__ __forceinline__ bf16x8 cvt8(const float4 a, const float4 b) {
    bf16x8 r;
    r[0] = (short)f2bf(a.x); r[1] = (short)f2bf(a.y);
    r[2] = (short)f2bf(a.z); r[3] = (short)f2bf(a.w);
    r[4] = (short)f2bf(b.x); r[5] = (short)f2bf(b.y);
    r[6] = (short)f2bf(b.z); r[7] = (short)f2bf(b.w);
    return r;
}

// ---------------------------------------------------------------------------
// Kernel 0: weights fp32 -> bf16, wbf[192][1024]
// ---------------------------------------------------------------------------
__global__ __launch_bounds__(256) void wconv_kernel(
    const float* __restrict__ wq, const float* __restrict__ wk,
    const float* __restrict__ wv, unsigned short* __restrict__ wbf)
{
    const int r = blockIdx.x;
    const float* src = (r < 64) ? wq : (r < 128) ? wk : wv;
    const int rr = r & 63;
    const int c  = threadIdx.x * 4;
    float4 a = *(const float4*)&src[(size_t)rr * BD + c];
    uint2 o;
    o.x = (unsigned)f2bf(a.x) | ((unsigned)f2bf(a.y) << 16);
    o.y = (unsigned)f2bf(a.z) | ((unsigned)f2bf(a.w) << 16);
    *(uint2*)&wbf[(size_t)r * BD + c] = o;
}

// ---------------------------------------------------------------------------
// Kernel 1: QKV projection, m97-style. 256 blocks x 4 waves, 64 rows/block.
// Waves split by OUTPUT tiles (wave w owns tiles 3w..3w+2 of 12); all waves
// share the x-tile. BK=64, double-buffered LDS: weights via async
// global_load_lds (XOR-swizzled on the global side), x manually staged
// fp32->bf16 (loads before compute, ds_write after -> latency hidden).
// Q written PRE-SCALED by 0.125*log2(e).
// ---------------------------------------------------------------------------
__global__ __launch_bounds__(256, 1) void qkv_kernel(
    const float* __restrict__ x,
    const unsigned short* __restrict__ wbf,
    unsigned short* __restrict__ Qb,
    unsigned short* __restrict__ Kb,
    unsigned short* __restrict__ Vt)
{
    const int r0   = blockIdx.x * 64;
    const int tid  = threadIdx.x;
    const int lane = tid & 63;
    const int w    = tid >> 6;
    const int g    = lane >> 4;
    const int c    = lane & 15;

    __shared__ __align__(16) unsigned short xb[2][64 * 64];    // 8 KB each
    __shared__ __align__(16) unsigned short wsh[2][192 * 64];  // 24 KB each
    __shared__ __align__(16) unsigned short vtr[64][72];       // V transpose

    f32x4 acc[3][4];
    #pragma unroll
    for (int t = 0; t < 3; ++t)
        #pragma unroll
        for (int rg = 0; rg < 4; ++rg) acc[t][rg] = (f32x4){0.f, 0.f, 0.f, 0.f};

    float4 xr[4];

    // ---- staging helpers (swizzle: lds[row][j] = global[row][j^(row&7)])
    #define STAGE_W(buf, k0s)                                                   \
        {                                                                       \
            _Pragma("unroll")                                                   \
            for (int ii = 0; ii < 6; ++ii) {                                    \
                const int L   = ii * 256 + tid;                                 \
                const int row = L >> 3;                                         \
                const int jl  = (L & 7) ^ (row & 7);                            \
                async_cp16(&wbf[(size_t)row * BD + (k0s) + jl * 8],             \
                           &wsh[buf][L * 8]);                                   \
            }                                                                   \
        }
    #define LOAD_X(k0s)                                                         \
        {                                                                       \
            _Pragma("unroll")                                                   \
            for (int p = 0; p < 2; ++p) {                                       \
                const int L   = p * 256 + tid;                                  \
                const int row = L >> 3;                                         \
                const int jl  = (L & 7) ^ (row & 7);                            \
                const float* s = &x[(size_t)(r0 + row) * BD + (k0s) + jl * 8];  \
                xr[p * 2]     = *(const float4*)s;                              \
                xr[p * 2 + 1] = *(const float4*)(s + 4);                        \
            }                                                                   \
        }
    #define WRITE_X(buf)                                                        \
        {                                                                       \
            _Pragma("unroll")                                                   \
            for (int p = 0; p < 2; ++p) {                                       \
                const int L = p * 256 + tid;                                    \
                *(bf16x8*)&xb[buf][L * 8] = cvt8(xr[p * 2], xr[p * 2 + 1]);     \
            }                                                                   \
        }

    STAGE_W(0, 0)
    LOAD_X(0)
    WRITE_X(0)

    for (int it = 0; it < 16; ++it) {
        const int cb = it & 1;
        __syncthreads();   // buf[cb] staged (vmcnt+lgkm drained by barrier)

        if (it < 15) {
            STAGE_W(cb ^ 1, (it + 1) * 64)   // async, no wave stall
            LOAD_X((it + 1) * 64)            // into regs, consumed after compute
        }

        #pragma unroll
        for (int h = 0; h < 2; ++h) {
            const int slot = ((h * 4 + g) ^ (c & 7)) * 8;
            bf16x8 aX[4], bW[3];
            #pragma unroll
            for (int rg = 0; rg < 4; ++rg)
                aX[rg] = *(const bf16x8*)&xb[cb][(rg * 16 + c) * 64 + slot];
            #pragma unroll
            for (int t = 0; t < 3; ++t)
                bW[t] = *(const bf16x8*)&wsh[cb][((w * 3 + t) * 16 + c) * 64 + slot];
            #pragma unroll
            for (int t = 0; t < 3; ++t)
                #pragma unroll
                for (int rg = 0; rg < 4; ++rg)
                    acc[t][rg] = __builtin_amdgcn_mfma_f32_16x16x32_bf16(
                        aX[rg], bW[t], acc[t][rg], 0, 0, 0);
        }

        if (it < 15) WRITE_X(cb ^ 1)   // waits on x loads; latency now hidden
    }

    // ---- epilogue.  C/D frag: row = rg*16 + g*4 + i, col = c (within tile m)
    const float qscale = 0.18033688f;   // 0.125 * log2(e)
    const int   bb     = r0 / TLEN;
    const int   trow   = r0 % TLEN;
    #pragma unroll
    for (int t = 0; t < 3; ++t) {
        const int m = w * 3 + t;
        #pragma unroll
        for (int rg = 0; rg < 4; ++rg)
            #pragma unroll
            for (int i = 0; i < 4; ++i) {
                const int row = rg * 16 + g * 4 + i;
                if (m < 4)
                    Qb[(size_t)(r0 + row) * HDIM + m * 16 + c]
                        = f2bf(acc[t][rg][i] * qscale);
                else if (m < 8)
                    Kb[(size_t)(r0 + row) * HDIM + (m - 4) * 16 + c]
                        = f2bf(acc[t][rg][i]);
                else
                    vtr[(m - 8) * 16 + c][row] = f2bf(acc[t][rg][i]);
            }
    }
    __syncthreads();   // vtr written by waves 2,3; read by all
    {
        const int d    = tid >> 2;
        const int part = tid & 3;
        uint4 v0 = *(const uint4*)&vtr[d][part * 16];
        uint4 v1 = *(const uint4*)&vtr[d][part * 16 + 8];
        unsigned short* dst = Vt + (size_t)bb * HDIM * TLEN + (size_t)d * TLEN
                            + trow + part * 16;
        *(uint4*)&dst[0] = v0;
        *(uint4*)&dst[8] = v1;
    }
    #undef STAGE_W
    #undef LOAD_X
    #undef WRITE_X
}

// ---------------------------------------------------------------------------
// Kernel 2: flash attention. 64q x 64k tiles, 4 waves (16q each),
// K/V double-buffered via global_load_lds w/ XOR row-swizzle,
// max-free softmax (logits bounded), exp2-only, deferred l-reduce.
// ---------------------------------------------------------------------------
template <int KEYS>
__global__ __launch_bounds__(256, 2) void attn_kernel(
    const unsigned short* __restrict__ Qb,
    const unsigned short* __restrict__ Kb,
    const unsigned short* __restrict__ Vt,
    float* __restrict__ O1, float* __restrict__ Ml, float* __restrict__ out)
{
    const int b     = blockIdx.y;
    const int q0    = blockIdx.x * 64;
    const int split = blockIdx.z;
    const int sbase = split * KEYS;

    const unsigned short* Qp = Qb + (size_t)b * TLEN * HDIM;
    const unsigned short* Kp = Kb + (size_t)b * TLEN * HDIM + (size_t)sbase * HDIM;
    const unsigned short* Vp = Vt + (size_t)b * HDIM * TLEN + sbase;

    const int tid  = threadIdx.x;
    const int lane = tid & 63;
    const int w    = tid >> 6;
    const int g    = lane >> 4;
    const int c    = lane & 15;

    __shared__ __align__(16) unsigned short ks[2][4096];
    __shared__ __align__(16) unsigned short vs[2][4096];
    __shared__ __align__(16) unsigned short pp[4][16 * 72];

    bf16x8 qA0 = *(const bf16x8*)&Qp[(size_t)(q0 + w * 16 + c) * HDIM + g * 8];
    bf16x8 qA1 = *(const bf16x8*)&Qp[(size_t)(q0 + w * 16 + c) * HDIM + 32 + g * 8];

    float lsum[4] = {0.f, 0.f, 0.f, 0.f};
    f32x4 oacc[4];
    #pragma unroll
    for (int t = 0; t < 4; ++t) oacc[t] = (f32x4){0.f, 0.f, 0.f, 0.f};

    const int nt = KEYS / 64;

    #pragma unroll
    for (int ii = 0; ii < 2; ++ii) {
        const int L   = ii * 256 + tid;
        const int row = L >> 3;
        const int jl  = (L & 7) ^ (row & 7);
        async_cp16(&Kp[(size_t)row * HDIM + jl * 8], &ks[0][L * 8]);
        async_cp16(&Vp[(size_t)row * TLEN + jl * 8], &vs[0][L * 8]);
    }

    for (int it = 0; it < nt; ++it) {
        const int cb = it & 1;
        __syncthreads();

        if (it + 1 < nt) {
            const int s0  = (it + 1) * 64;
            const int nb2 = cb ^ 1;
            #pragma unroll
            for (int ii = 0; ii < 2; ++ii) {
                const int L   = ii * 256 + tid;
                const int row = L >> 3;
                const int jl  = (L & 7) ^ (row & 7);
                async_cp16(&Kp[(size_t)(s0 + row) * HDIM + jl * 8], &ks[nb2][L * 8]);
                async_cp16(&Vp[(size_t)row * TLEN + s0 + jl * 8],   &vs[nb2][L * 8]);
            }
        }

        f32x4 sacc[4];
        #pragma unroll
        for (int t = 0; t < 4; ++t) sacc[t] = (f32x4){0.f, 0.f, 0.f, 0.f};
        #pragma unroll
        for (int t = 0; t < 4; ++t) {
            const int r  = 16 * t + c;
            const int j0 = g ^ (r & 7);
            bf16x8 kB0 = *(const bf16x8*)&ks[cb][(r * 8 + j0) * 8];
            bf16x8 kB1 = *(const bf16x8*)&ks[cb][(r * 8 + (j0 ^ 4)) * 8];
            sacc[t] = __builtin_amdgcn_mfma_f32_16x16x32_bf16(qA0, kB0, sacc[t], 0, 0, 0);
            sacc[t] = __builtin_amdgcn_mfma_f32_16x16x32_bf16(qA1, kB1, sacc[t], 0, 0, 0);
        }

        #pragma unroll
        for (int i = 0; i < 4; ++i) {
            float p0 = __builtin_amdgcn_exp2f(sacc[0][i]);
            float p1 = __builtin_amdgcn_exp2f(sacc[1][i]);
            float p2 = __builtin_amdgcn_exp2f(sacc[2][i]);
            float p3 = __builtin_amdgcn_exp2f(sacc[3][i]);
            unsigned u0 = __float_as_uint(p0) & 0xffff0000u;
            unsigned u1 = __float_as_uint(p1) & 0xffff0000u;
            unsigned u2 = __float_as_uint(p2) & 0xffff0000u;
            unsigned u3 = __float_as_uint(p3) & 0xffff0000u;
            lsum[i] += (__uint_as_float(u0) + __uint_as_float(u1))
                     + (__uint_as_float(u2) + __uint_as_float(u3));
            unsigned short* pr = &pp[w][(g * 4 + i) * 72 + c];
            pr[0]  = (unsigned short)(u0 >> 16);
            pr[16] = (unsigned short)(u1 >> 16);
            pr[32] = (unsigned short)(u2 >> 16);
            pr[48] = (unsigned short)(u3 >> 16);
        }

        bf16x8 pA0 = *(const bf16x8*)&pp[w][c * 72 + g * 8];
        bf16x8 pA1 = *(const bf16x8*)&pp[w][c * 72 + 32 + g * 8];
        #pragma unroll
        for (int t = 0; t < 4; ++t) {
            const int r  = 16 * t + c;
            const int j0 = g ^ (r & 7);
            bf16x8 vB0 = *(const bf16x8*)&vs[cb][(r * 8 + j0) * 8];
            bf16x8 vB1 = *(const bf16x8*)&vs[cb][(r * 8 + (j0 ^ 4)) * 8];
            oacc[t] = __builtin_amdgcn_mfma_f32_16x16x32_bf16(pA0, vB0, oacc[t], 0, 0, 0);
            oacc[t] = __builtin_amdgcn_mfma_f32_16x16x32_bf16(pA1, vB1, oacc[t], 0, 0, 0);
        }
    }

    #pragma unroll
    for (int i = 0; i < 4; ++i) {
        lsum[i] += __shfl_xor(lsum[i], 1);
        lsum[i] += __shfl_xor(lsum[i], 2);
        lsum[i] += __shfl_xor(lsum[i], 4);
        lsum[i] += __shfl_xor(lsum[i], 8);
    }

    const size_t orow = (size_t)(b * TLEN + q0 + w * 16 + g * 4);
    if (KEYS == TLEN) {
        #pragma unroll
        for (int i = 0; i < 4; ++i) {
            const float inv = 1.0f / lsum[i];
            #pragma unroll
            for (int t = 0; t < 4; ++t)
                out[(orow + i) * HDIM + 16 * t + c] = oacc[t][i] * inv;
        }
    } else {
        float* Od = (split == 0) ? out : O1;
        #pragma unroll
        for (int i = 0; i < 4; ++i)
            #pragma unroll
            for (int t = 0; t < 4; ++t)
                Od[(orow + i) * HDIM + 16 * t + c] = oacc[t][i];
        if (c == 0) {
            #pragma unroll
            for (int i = 0; i < 4; ++i)
                Ml[(size_t)(split * NB + b) * TLEN + q0 + w * 16 + g * 4 + i] = lsum[i];
        }
    }
}

// ---------------------------------------------------------------------------
// Kernel 3: merge splits: out = (O0 + O1) / (l0 + l1)
// ---------------------------------------------------------------------------
__global__ __launch_bounds__(256) void merge_kernel(
    float* __restrict__ out, const float* __restrict__ O1,
    const float* __restrict__ Ml)
{
    const int idx  = blockIdx.x * 256 + threadIdx.x;
    const int row  = idx >> 4;
    const int col4 = (idx & 15) * 4;
    const int b    = row >> 12;
    const int t    = row & (TLEN - 1);
    const float l0 = Ml[(size_t)b * TLEN + t];
    const float l1 = Ml[(size_t)(NB + b) * TLEN + t];
    const float inv = 1.0f / (l0 + l1);
    float4 a  = *(const float4*)&out[(size_t)row * HDIM + col4];
    float4 bq = *(const float4*)&O1[(size_t)row * HDIM + col4];
    float4 r;
    r.x = (a.x + bq.x) * inv;
    r.y = (a.y + bq.y) * inv;
    r.z = (a.z + bq.z) * inv;
    r.w = (a.w + bq.w) * inv;
    *(float4*)&out[(size_t)row * HDIM + col4] = r;
}

// ---------------------------------------------------------------------------
extern "C" void kernel_launch(void* const* d_in, const int* in_sizes, int n_in,
                              void* d_out, int out_size, void* d_ws, size_t ws_size,
                              hipStream_t stream)
{
    (void)in_sizes; (void)n_in; (void)out_size;
    const float* x  = (const float*)d_in[0];
    const float* wq = (const float*)d_in[1];
    const float* wk = (const float*)d_in[2];
    const float* wv = (const float*)d_in[3];
    float* out = (float*)d_out;

    unsigned short* wbf = (unsigned short*)d_out;     // parked; consumed by qkv
    unsigned short* Qbf = (unsigned short*)d_ws;
    unsigned short* Kbf = Qbf + (size_t)NB * TLEN * HDIM;
    unsigned short* Vtb = Kbf + (size_t)NB * TLEN * HDIM;
    float* Ml = (float*)((char*)d_ws + (size_t)3 * NB * TLEN * HDIM * 2);
    float* O1 = Ml + (size_t)2 * NB * TLEN;
    const size_t ws_need_split = (size_t)3 * NB * TLEN * HDIM * 2
                               + (size_t)2 * NB * TLEN * 4
                               + (size_t)NB * TLEN * HDIM * 4;
    const bool use_split = ws_size >= ws_need_split;

    wconv_kernel<<<dim3(192), 256, 0, stream>>>(wq, wk, wv, wbf);
    qkv_kernel<<<dim3(NB * TLEN / 64), 256, 0, stream>>>(x, wbf, Qbf, Kbf, Vtb);

    if (use_split) {
        attn_kernel<TLEN / 2><<<dim3(TLEN / 64, NB, 2), 256, 0, stream>>>(
            Qbf, Kbf, Vtb, O1, Ml, out);
        merge_kernel<<<dim3(NB * TLEN * 16 / 256), 256, 0, stream>>>(out, O1, Ml);
    } else {
        attn_kernel<TLEN><<<dim3(TLEN / 64, NB, 1), 256, 0, stream>>>(
            Qbf, Kbf, Vtb, O1, Ml, out);
    }
}